// Round 1
// baseline (566.339 us; speedup 1.0000x reference)
//
#include <hip/hip_runtime.h>

typedef __attribute__((ext_vector_type(8))) short short8;
typedef __attribute__((ext_vector_type(4))) float f32x4;

#define MFMA16(A,B,C) __builtin_amdgcn_mfma_f32_16x16x32_bf16(A,B,C,0,0,0)

__device__ __forceinline__ short f2bf(float f){
  union { float f; unsigned int u; } v; v.f = f;
  unsigned int u = v.u;
  unsigned int r = (u + 0x7fffu + ((u >> 16) & 1u)) >> 16;
  return (short)r;
}

typedef const __attribute__((address_space(1))) void* gptr_t;
typedef __attribute__((address_space(3))) void* lptr_t;

__device__ __forceinline__ void gload16(const short* g, short* l){
  __builtin_amdgcn_global_load_lds((gptr_t)g, (lptr_t)l, 16, 0, 0);
}

// ---------------- converts ----------------

__global__ __launch_bounds__(256) void cvt_x_kernel(const float* __restrict__ x,
                                                    short* __restrict__ xb){
  const size_t i = (size_t)blockIdx.x * 256 + threadIdx.x;
  const float4* p = (const float4*)x + i * 2;
  float4 a = p[0], b = p[1];
  short8 o;
  o[0]=f2bf(a.x); o[1]=f2bf(a.y); o[2]=f2bf(a.z); o[3]=f2bf(a.w);
  o[4]=f2bf(b.x); o[5]=f2bf(b.y); o[6]=f2bf(b.z); o[7]=f2bf(b.w);
  *(short8*)(xb + i * 8) = o;
}

// src[R][C] f32 -> dst[C][R] bf16
__global__ __launch_bounds__(256) void cvt_t_kernel(const float* __restrict__ src,
                                                    short* __restrict__ dst,
                                                    int R, int C){
  __shared__ float tile[32][33];
  const int tx = threadIdx.x, ty = threadIdx.y;
  const int c0 = blockIdx.x * 32, r0 = blockIdx.y * 32;
  #pragma unroll
  for (int i = 0; i < 32; i += 8)
    tile[ty + i][tx] = src[(size_t)(r0 + ty + i) * C + c0 + tx];
  __syncthreads();
  #pragma unroll
  for (int i = 0; i < 32; i += 8)
    dst[(size_t)(c0 + ty + i) * R + r0 + tx] = f2bf(tile[tx][ty + i]);
}

// ---------------- GEMM: C[M][N] = A[M][1024] * BT[N][1024]^T + bias ----------------
// EPI 0: QKV epilogue -> scatter q_ws[n,h,l,d], k_ws[n,h,l,d], vt_ws[n,h,d,l] (bf16)
// EPI 1: out epilogue -> Cf f32 [M][1024]

template<int EPI>
__global__ __launch_bounds__(256) void gemm_bt(
    const short* __restrict__ A, const short* __restrict__ BT,
    const float* __restrict__ bias,
    float* __restrict__ Cf,
    short* __restrict__ q_ws, short* __restrict__ k_ws, short* __restrict__ vt_ws)
{
  __shared__ __align__(16) short As[4096];  // [128][32]
  __shared__ __align__(16) short Bs[4096];  // [128][32]
  const int tid = threadIdx.x;
  const int bm = blockIdx.x, bn = blockIdx.y;
  const int lane = tid & 63, wid = tid >> 6;
  const int wr = wid >> 1, wc = wid & 1;
  const int r = lane & 15, g = lane >> 4;

  f32x4 acc[4][4] = {};

  const short* ag = A  + (size_t)(bm * 128 + (tid >> 2)) * 1024 + (tid & 3) * 8;
  const short* bg = BT + (size_t)(bn * 128 + (tid >> 2)) * 1024 + (tid & 3) * 8;
  short* asd = &As[tid * 8];
  short* bsd = &Bs[tid * 8];

  for (int kk = 0; kk < 32; ++kk){
    gload16(ag + kk * 32,             asd);
    gload16(ag + kk * 32 + 64 * 1024, asd + 2048);
    gload16(bg + kk * 32,             bsd);
    gload16(bg + kk * 32 + 64 * 1024, bsd + 2048);
    asm volatile("s_waitcnt vmcnt(0)" ::: "memory");
    __syncthreads();
    short8 a[4], b[4];
    #pragma unroll
    for (int mf = 0; mf < 4; ++mf)
      a[mf] = *(const short8*)&As[(wr * 64 + mf * 16 + r) * 32 + g * 8];
    #pragma unroll
    for (int nf = 0; nf < 4; ++nf)
      b[nf] = *(const short8*)&Bs[(wc * 64 + nf * 16 + r) * 32 + g * 8];
    #pragma unroll
    for (int mf = 0; mf < 4; ++mf)
      #pragma unroll
      for (int nf = 0; nf < 4; ++nf)
        acc[mf][nf] = MFMA16(a[mf], b[nf], acc[mf][nf]);
    __syncthreads();
  }

  if (EPI == 0){
    #pragma unroll
    for (int nf = 0; nf < 4; ++nf){
      const int c = bn * 128 + wc * 64 + nf * 16 + r;
      const float bv = bias[c];
      const int type = c >> 10;
      const int h = (c & 1023) >> 6, d = c & 63;
      #pragma unroll
      for (int mf = 0; mf < 4; ++mf){
        const int row0 = bm * 128 + wr * 64 + mf * 16 + g * 4;
        const int nb = row0 >> 11, l0 = row0 & 2047;
        f32x4 v = acc[mf][nf];
        if (type == 2){
          short4 pk;
          pk.x = f2bf(v[0] + bv); pk.y = f2bf(v[1] + bv);
          pk.z = f2bf(v[2] + bv); pk.w = f2bf(v[3] + bv);
          *(short4*)&vt_ws[((size_t)(nb * 16 + h) * 64 + d) * 2048 + l0] = pk;
        } else {
          short* dst = (type == 0) ? q_ws : k_ws;
          const size_t base = ((size_t)(nb * 16 + h) * 2048 + l0) * 64 + d;
          #pragma unroll
          for (int j = 0; j < 4; ++j) dst[base + (size_t)j * 64] = f2bf(v[j] + bv);
        }
      }
    }
  } else {
    #pragma unroll
    for (int nf = 0; nf < 4; ++nf){
      const int c = bn * 128 + wc * 64 + nf * 16 + r;
      const float bv = bias[c];
      #pragma unroll
      for (int mf = 0; mf < 4; ++mf){
        const int row0 = bm * 128 + wr * 64 + mf * 16 + g * 4;
        f32x4 v = acc[mf][nf];
        #pragma unroll
        for (int j = 0; j < 4; ++j)
          Cf[(size_t)(row0 + j) * 1024 + c] = v[j] + bv;
      }
    }
  }
}

// ---------------- flash attention ----------------
// q_ws,k_ws: [64 heads][2048][64] bf16 ; vt_ws: [64 heads][64][2048] bf16
// o_ws: [4][2048][1024] bf16 (rows n*2048+l, cols h*64+d)

__global__ __launch_bounds__(256) void attn_kernel(
    const short* __restrict__ qw, const short* __restrict__ kw,
    const short* __restrict__ vtw, short* __restrict__ ow)
{
  __shared__ __align__(16) short P[4][1024];  // per-wave 16x64 bf16, XOR-swizzled
  const int id = blockIdx.x;
  // XCD swizzle: all 32 q-tiles of a head land on the same XCD
  const int xcd = id & 7, hi = (id >> 3) & 7;
  const int nh = xcd * 8 + hi;
  const int qt = id >> 6;
  const int tid = threadIdx.x;
  const int lane = tid & 63, w = tid >> 6;
  const int r = lane & 15, g = lane >> 4;

  const size_t hoff = (size_t)nh * 2048 * 64;
  const short* qh = qw + hoff + (size_t)(qt * 64 + w * 16 + r) * 64;
  const short* kh = kw + hoff;
  const short* vh = vtw + hoff;

  short8 qf0 = *(const short8*)(qh + g * 8);
  short8 qf1 = *(const short8*)(qh + 32 + g * 8);

  float m[4]    = {-1e30f, -1e30f, -1e30f, -1e30f};
  float lsum[4] = {0.f, 0.f, 0.f, 0.f};
  f32x4 oa[4] = {};
  const float sc = 0.125f * 1.4426950408889634f;  // scale * log2(e)
  short* Pw = &P[w][0];

  for (int kt = 0; kt < 32; ++kt){
    // S = Q K^T  (16q x 64k per wave)
    f32x4 s[4];
    #pragma unroll
    for (int cb = 0; cb < 4; ++cb){
      const short* kr = kh + (size_t)(kt * 64 + cb * 16 + r) * 64;
      short8 kf0 = *(const short8*)(kr + g * 8);
      short8 kf1 = *(const short8*)(kr + 32 + g * 8);
      f32x4 t = {0.f, 0.f, 0.f, 0.f};
      t = MFMA16(qf0, kf0, t);
      t = MFMA16(qf1, kf1, t);
      s[cb] = t;
    }
    // row max (across 16 cols per cb, then across 16 lanes of the group)
    float mx[4];
    #pragma unroll
    for (int j = 0; j < 4; ++j){
      mx[j] = fmaxf(fmaxf(s[0][j], s[1][j]), fmaxf(s[2][j], s[3][j]));
      mx[j] = fmaxf(mx[j], __shfl_xor(mx[j], 1));
      mx[j] = fmaxf(mx[j], __shfl_xor(mx[j], 2));
      mx[j] = fmaxf(mx[j], __shfl_xor(mx[j], 4));
      mx[j] = fmaxf(mx[j], __shfl_xor(mx[j], 8));
    }
    float al[4], rs[4];
    #pragma unroll
    for (int j = 0; j < 4; ++j){
      float ms = mx[j] * sc;
      float mn = fmaxf(m[j], ms);
      al[j] = exp2f(m[j] - mn);
      m[j] = mn;
      rs[j] = 0.f;
    }
    // P = exp2(s*sc - m), accumulate row sums, write swizzled LDS
    #pragma unroll
    for (int cb = 0; cb < 4; ++cb){
      const int col = cb * 16 + r;
      #pragma unroll
      for (int j = 0; j < 4; ++j){
        float p = exp2f(s[cb][j] * sc - m[j]);
        rs[j] += p;
        const int row = g * 4 + j;
        Pw[row * 64 + (col ^ ((row & 7) << 3))] = f2bf(p);
      }
    }
    #pragma unroll
    for (int j = 0; j < 4; ++j){
      rs[j] += __shfl_xor(rs[j], 1);
      rs[j] += __shfl_xor(rs[j], 2);
      rs[j] += __shfl_xor(rs[j], 4);
      rs[j] += __shfl_xor(rs[j], 8);
      lsum[j] = lsum[j] * al[j] + rs[j];
    }
    #pragma unroll
    for (int db = 0; db < 4; ++db)
      #pragma unroll
      for (int j = 0; j < 4; ++j) oa[db][j] *= al[j];

    __builtin_amdgcn_wave_barrier();
    // PV: O[16q x 64d] += P[16x64] * V[64k x 64d]
    short8 p0 = *(const short8*)(Pw + r * 64 + ((g * 8) ^ ((r & 7) << 3)));
    short8 p1 = *(const short8*)(Pw + r * 64 + ((32 + g * 8) ^ ((r & 7) << 3)));
    #pragma unroll
    for (int db = 0; db < 4; ++db){
      const short* vr = vh + (size_t)(db * 16 + r) * 2048 + kt * 64;
      short8 vf0 = *(const short8*)(vr + g * 8);
      short8 vf1 = *(const short8*)(vr + 32 + g * 8);
      oa[db] = MFMA16(p0, vf0, oa[db]);
      oa[db] = MFMA16(p1, vf1, oa[db]);
    }
    __builtin_amdgcn_wave_barrier();
  }

  const int n = nh >> 4, h = nh & 15;
  float inv[4];
  #pragma unroll
  for (int j = 0; j < 4; ++j) inv[j] = 1.0f / lsum[j];
  #pragma unroll
  for (int db = 0; db < 4; ++db)
    #pragma unroll
    for (int j = 0; j < 4; ++j){
      const float val = oa[db][j] * inv[j];
      ow[((size_t)n * 2048 + qt * 64 + w * 16 + g * 4 + j) * 1024 + h * 64 + db * 16 + r]
        = f2bf(val);
    }
}

// ---------------- launch ----------------

extern "C" void kernel_launch(void* const* d_in, const int* in_sizes, int n_in,
                              void* d_out, int out_size, void* d_ws, size_t ws_size,
                              hipStream_t stream){
  const float* attn_in = (const float*)d_in[0];
  const float* W_qkv   = (const float*)d_in[1];
  const float* b_qkv   = (const float*)d_in[2];
  const float* W_out   = (const float*)d_in[3];
  const float* b_out   = (const float*)d_in[4];
  float* out = (float*)d_out;

  char* ws = (char*)d_ws;
  short* xb    = (short*)(ws);              // 16 MB  [8192][1024]
  short* wqT   = (short*)(ws + 16777216);   // 6 MB   [3072][1024]
  short* woT   = (short*)(ws + 23068672);   // 2 MB   [1024][1024]
  short* q_ws  = (short*)(ws + 25165824);   // 16 MB  [64][2048][64]
  short* k_ws  = (short*)(ws + 41943040);   // 16 MB
  short* vt_ws = (short*)(ws + 58720256);   // 16 MB  [64][64][2048]
  short* o_ws  = (short*)(ws + 75497472);   // 16 MB  [8192][1024]

  cvt_x_kernel<<<4096, 256, 0, stream>>>(attn_in, xb);
  cvt_t_kernel<<<dim3(96, 32), dim3(32, 8), 0, stream>>>(W_qkv, wqT, 1024, 3072);
  cvt_t_kernel<<<dim3(32, 32), dim3(32, 8), 0, stream>>>(W_out, woT, 1024, 1024);
  gemm_bt<0><<<dim3(64, 24), 256, 0, stream>>>(xb, wqT, b_qkv, nullptr, q_ws, k_ws, vt_ws);
  attn_kernel<<<2048, 256, 0, stream>>>(q_ws, k_ws, vt_ws, o_ws);
  gemm_bt<1><<<dim3(64, 8), 256, 0, stream>>>(o_ws, woT, b_out, out, nullptr, nullptr, nullptr);
}